// Round 4
// baseline (290.073 us; speedup 1.0000x reference)
//
#include <hip/hip_runtime.h>

// KinematicWaveRouting: the reference recurrence
//   Q[j] <- max(Q[j] - CFL*(Q[j]-Q[j-1]) + u(t), 0),  CFL = 0.9, Q[0] = 0
// is linear (all terms nonnegative => max never binds). Outlet (Q[20]) is a
// causal FIR: outlet(t) = basin_area*50 * sum_k w[k]*runoff(t-k), K=32 taps
// (w decays ~10x/step past k~21; truncation error << threshold).
//
// R4 -> R6: LDS abandoned. R3 (XOR-swizzled) had 2.5e7 bank-conflict cycles;
// R4 (linear) had 3.1e7 and dur tracked conflicts (84->100us) -- the b128
// bank-phase grouping defeated both layouts and is not directly observable.
// But LDS was only serving a 9x window re-read whose per-wave working set is
// 1.15 KB -- trivially L1-resident. So: read the 9-quad window straight from
// global at the same lane-contiguous pattern (each ds_read replaced by a
// fully-coalesced 1024B global_load_dwordx4, 8/9 of them L1 hits). Deletes
// staging, __syncthreads, LDS alloc, and the whole conflict question.
// Floors: HBM ~32us (FETCH 66MB is L3-served + WRITE 134MB), VALU ~14us.

#define KTAPS 32
#define TPB   256
#define TILE_T 2048                  // t-values per block (512 output quads)

struct WTab { float w[KTAPS]; };

__global__ __launch_bounds__(TPB) void kwr_fir_kernel(
    const float* __restrict__ runoff,
    const float* __restrict__ basin_area,
    float* __restrict__ out,
    int T, int tiles_per_row, WTab wt)
{
    const int tid  = threadIdx.x;
    const int lane = tid & 63;
    const int wv   = tid >> 6;
    const int blk  = blockIdx.x;
    const int b    = blk / tiles_per_row;
    const int tile = blk - b * tiles_per_row;
    const long long rowbase = (long long)b * T;

    const float s = basin_area[b] * 50.0f;   // (1e6/1000/3600/20) * DT

    const float4* grow = (const float4*)(runoff + rowbase);
    float4*       orow = (float4*)(out + rowbase);
    const int qbase = tile * (TILE_T / 4);

    // Two lane-contiguous output quads per thread. Row-local output quad
    // j = qbase + 128*wv + 64*g + lane; output float p = 4j+r needs
    // x[p-31..p] = win[1..35] where win[m] = x[4*(j-8)+m]; tap k for float r
    // uses win[32 + r - k]. Window loads grow[j-8+c], c=0..8: 64 consecutive
    // quads per wave per phase = 1024B fully coalesced, L1-served overlap.
    #pragma unroll
    for (int g = 0; g < 2; ++g) {
        const int j = qbase + 128 * wv + 64 * g + lane;
        const float4* wsrc = grow + (j - 8);

        float win[36];
        if (j >= 8) {                         // all waves except row head
            #pragma unroll
            for (int c = 0; c < 9; ++c) {
                float4 v = wsrc[c];
                win[4*c+0] = v.x; win[4*c+1] = v.y;
                win[4*c+2] = v.z; win[4*c+3] = v.w;
            }
        } else {                              // t<0 halo: x = 0
            #pragma unroll
            for (int c = 0; c < 9; ++c) {
                float4 v = (j - 8 + c >= 0) ? wsrc[c]
                                            : make_float4(0.f, 0.f, 0.f, 0.f);
                win[4*c+0] = v.x; win[4*c+1] = v.y;
                win[4*c+2] = v.z; win[4*c+3] = v.w;
            }
        }

        float a0 = 0.f, a1 = 0.f, a2 = 0.f, a3 = 0.f;
        #pragma unroll
        for (int k = 0; k < KTAPS; ++k) {
            const float wk = wt.w[k];
            a0 = fmaf(wk, win[32 - k], a0);
            a1 = fmaf(wk, win[33 - k], a1);
            a2 = fmaf(wk, win[34 - k], a2);
            a3 = fmaf(wk, win[35 - k], a3);
        }

        orow[j] = make_float4(a0 * s, a1 * s, a2 * s, a3 * s);
    }
}

extern "C" void kernel_launch(void* const* d_in, const int* in_sizes, int n_in,
                              void* d_out, int out_size, void* d_ws, size_t ws_size,
                              hipStream_t stream)
{
    const float* runoff     = (const float*)d_in[0];
    const float* basin_area = (const float*)d_in[1];
    float* out = (float*)d_out;

    const int B = in_sizes[1];            // basin_area has B elements
    const int T = in_sizes[0] / B;        // runoff is (B, T)

    // Impulse response of the linear recurrence, computed in double.
    WTab wt;
    double Q[21];
    for (int j = 0; j <= 20; ++j) Q[j] = (j >= 1) ? 1.0 : 0.0;
    wt.w[0] = 1.0f;
    for (int k = 1; k < KTAPS; ++k) {
        for (int j = 20; j >= 1; --j) Q[j] = 0.1 * Q[j] + 0.9 * Q[j - 1];
        wt.w[k] = (float)Q[20];
    }

    const int tiles_per_row = T / TILE_T;           // 4096 / 2048 = 2
    const int nblk = B * tiles_per_row;             // 16384

    kwr_fir_kernel<<<nblk, TPB, 0, stream>>>(runoff, basin_area, out,
                                             T, tiles_per_row, wt);
}